// Round 12
// baseline (295.622 us; speedup 1.0000x reference)
//
#include <hip/hip_runtime.h>
#include <math.h>

#define EPS_BN 1e-5

namespace {

constexpr double CNT1 = 4096.0 * 1024.0;  // layer1 BN count: B*32*32
constexpr double CNT2 = 4096.0 * 256.0;   // layer2 BN count: B*16*16

// workspace layout (bytes). Required ws >= ~131 MiB.
constexpr size_t OFF_Y1 = 0;            // [4096,1024px,8ch] f16 = 64 MiB (live thru conv2)
constexpr size_t OFF_Y2 = 67108864;     // [4096,16ch,256px] f16 = 32 MiB
constexpr size_t OFF_H2 = 100663296;    // [4096,2048] bf16 = 16 MiB
constexpr size_t OFF_A1 = 117440512;    // [4096,512] bf16 = 4 MiB
constexpr size_t OFF_A2 = 121634816;    // [4096,512] f32 = 8 MiB
constexpr size_t OFF_ST = 134217728;    // BN stats: 208 slots x 64B (13312 B)
constexpr size_t OFF_WT = 134234112;    // conv1 weights transposed [27][8] f32 (in ST region slack)
constexpr size_t OFF_WB1 = 134283264;   // fc1_w bf16 [512,2048] = 2 MiB
constexpr size_t OFF_WB2 = 136380416;   // fc2_w bf16 [512,512] = 0.5 MiB

#define STG(p, i) (p)[(size_t)(i) * 8]

typedef short bf16x8 __attribute__((ext_vector_type(8)));
typedef float f32x4 __attribute__((ext_vector_type(4)));
typedef _Float16 f16;
typedef _Float16 f16x2 __attribute__((ext_vector_type(2)));
typedef _Float16 f16x4 __attribute__((ext_vector_type(4)));
typedef _Float16 f16x8 __attribute__((ext_vector_type(8)));

__device__ __forceinline__ short f2bf(float f) {
  unsigned u = __float_as_uint(f);
  u = (u + 0x7fffu + ((u >> 16) & 1u)) >> 16;
  return (short)u;
}

// LDS-transpose block stats for 8 channels (s+q = 16 values/thread).
// sred must be >= 16*257 floats, untouched before the call.
// Atomic slot layout: STG slot 2c = s[c], 2c+1 = q[c].
__device__ __forceinline__ void block_stats_lds(const float* s, const float* q,
                                                float* __restrict__ sred,
                                                double* __restrict__ st) {
  const int tid = threadIdx.x;
#pragma unroll
  for (int j = 0; j < 8; ++j) {
    sred[j * 257 + tid] = s[j];        // bank = (j + tid)%32: conflict-free
    sred[(j + 8) * 257 + tid] = q[j];
  }
  __syncthreads();
  const int row = tid >> 4, seg = tid & 15;  // row = stat idx 0..15
  float p = 0.f;
#pragma unroll
  for (int k = 0; k < 16; ++k) {
    const int ke = (k + seg) & 15;  // swizzle to spread banks
    p += sred[row * 257 + seg * 16 + ke];
  }
  p += __shfl_down(p, 8, 64);
  p += __shfl_down(p, 4, 64);
  p += __shfl_down(p, 2, 64);
  p += __shfl_down(p, 1, 64);
  if (seg == 0) {
    const int c = (row < 8) ? row : row - 8;
    const int slot = (row < 8) ? 2 * c : 2 * c + 1;
    unsafeAtomicAdd(st + (size_t)slot * 8, (double)p);
  }
}

__device__ __forceinline__ float wave_sum(float v) {
#pragma unroll
  for (int o = 32; o > 0; o >>= 1) v += __shfl_down(v, o, 64);
  return v;
}

// ---------------- layer 1: conv 3x3, 3->8, on 32x32, pad 1 -------------------
// R21 "co-split + direct-neighbor loads": thread = full column x co-PAIR;
// wave = wave-uniform co-pair g, 2 images x 32 cols; block = 4 waves =
// 2 images; grid 2048. R11 left a 61us kernel at 37% VALUBusy — the last
// serial element per step was 6 ds_bpermute (neighbor-col shuffles) on the
// LDS pipe. This round removes them: xl/xm/xr are loaded DIRECTLY from
// global (4B-adjacent, L1-served), with per-lane clamped offsets dl/dr and
// zero-pad via multiply masks ml/mr — no divergent branches, no LDS, no
// shuffles, no loop-carried x state. Each step = 9 independent vmem loads
// + 6 muls + 54 SGPR-weight fmacs; compiler hoists loads across steps
// (counted vmcnt) for deep MLP. 54 weights hoisted to SGPRs once (R20).
// 3-phase static acc rotation (R7-proven). Stores pack 2 f16 -> one dword.
// Stats 8-sub-banked by blockIdx&7. Writes y1 f16 NHWC [n][1024px][8ch].
__global__ __launch_bounds__(256) void k_conv1_y1(
    const float* __restrict__ x, const float* __restrict__ wt,
    f16* __restrict__ y1, double* __restrict__ st1) {
  __shared__ float sred[16 * 65];  // 4.2 KB stats transpose
  const int tid = threadIdx.x;
  const int g = __builtin_amdgcn_readfirstlane(tid >> 6);  // co-pair 0..3
  const int lane = tid & 63;
  const int img = lane >> 5, c = lane & 31;
  const int n = blockIdx.x * 2 + img;
  const int co0 = 2 * g;
  const float* xp = x + (size_t)n * 3072 + c;  // [3][32][32], this column
  f16* yp = y1 + (size_t)n * 8192;
  // neighbor-column access: clamped offset + zero mask (no divergence)
  const int dl = (c > 0) ? -1 : 0;
  const int dr = (c < 31) ? 1 : 0;
  const float mlm = (c > 0) ? 1.f : 0.f;
  const float mrm = (c < 31) ? 1.f : 0.f;
  // hoist this wave's 54 weights (wave-uniform addr -> s_load, resident)
  float wA[27], wB[27];
#pragma unroll
  for (int t = 0; t < 27; ++t) {
    wA[t] = wt[t * 8 + co0];
    wB[t] = wt[t * 8 + co0 + 1];
  }
  float a0[2], a1[2], a2[2], s[2], q[2];
#pragma unroll
  for (int j = 0; j < 2; ++j) {
    a0[j] = 0.f; a1[j] = 0.f; a2[j] = 0.f; s[j] = 0.f; q[j] = 0.f;
  }

#define CONTRIB(ACC, T, XV)                                           \
  {                                                                   \
    ACC[0] += wA[T] * (XV);                                           \
    ACC[1] += wB[T] * (XV);                                           \
  }

  // STEP(R): load x-row R (3 ch x {l,m,r}), fmac into 3 rotating accs,
  // complete y-row R-1 (gate R>=1). Row R==32 is the zero phantom row.
  // AP = y[R-1], AC = y[R], AN = y[R+1].
#define STEP(R, AP, AC, AN)                                           \
  {                                                                   \
    float xm0 = 0.f, xl0 = 0.f, xr0 = 0.f;                            \
    float xm1 = 0.f, xl1 = 0.f, xr1 = 0.f;                            \
    float xm2 = 0.f, xl2 = 0.f, xr2 = 0.f;                            \
    if ((R) < 32) {                                                   \
      const float* rp = xp + (R) * 32;                                \
      xm0 = rp[0];    xl0 = rp[dl] * mlm;    xr0 = rp[dr] * mrm;      \
      xm1 = rp[1024]; xl1 = rp[1024 + dl] * mlm;                      \
      xr1 = rp[1024 + dr] * mrm;                                      \
      xm2 = rp[2048]; xl2 = rp[2048 + dl] * mlm;                      \
      xr2 = rp[2048 + dr] * mrm;                                      \
    }                                                                 \
    CONTRIB(AN, 0, xl0); CONTRIB(AN, 1, xm0); CONTRIB(AN, 2, xr0);    \
    CONTRIB(AC, 3, xl0); CONTRIB(AC, 4, xm0); CONTRIB(AC, 5, xr0);    \
    CONTRIB(AP, 6, xl0); CONTRIB(AP, 7, xm0); CONTRIB(AP, 8, xr0);    \
    CONTRIB(AN, 9, xl1); CONTRIB(AN, 10, xm1); CONTRIB(AN, 11, xr1);  \
    CONTRIB(AC, 12, xl1); CONTRIB(AC, 13, xm1); CONTRIB(AC, 14, xr1); \
    CONTRIB(AP, 15, xl1); CONTRIB(AP, 16, xm1); CONTRIB(AP, 17, xr1); \
    CONTRIB(AN, 18, xl2); CONTRIB(AN, 19, xm2); CONTRIB(AN, 20, xr2); \
    CONTRIB(AC, 21, xl2); CONTRIB(AC, 22, xm2); CONTRIB(AC, 23, xr2); \
    CONTRIB(AP, 24, xl2); CONTRIB(AP, 25, xm2); CONTRIB(AP, 26, xr2); \
    if ((R) >= 1) {                                                   \
      float v0 = AP[0], v1 = AP[1];                                   \
      s[0] += v0; q[0] += v0 * v0;                                    \
      s[1] += v1; q[1] += v1 * v1;                                    \
      f16 hv[2] = {(f16)v0, (f16)v1};                                 \
      *(unsigned*)&yp[(size_t)((R) - 1) * 256 + c * 8 + co0] =        \
          *(unsigned*)hv;                                             \
    }                                                                 \
    AP[0] = 0.f; AP[1] = 0.f;                                         \
  }

  for (int rb = 0; rb < 33; rb += 3) {
    STEP(rb,     a2, a0, a1);  // R%3==0: y[R-1]->a2, y[R]->a0, y[R+1]->a1
    STEP(rb + 1, a0, a1, a2);
    STEP(rb + 2, a1, a2, a0);
  }
#undef STEP
#undef CONTRIB
  // stats: each thread holds s,q for co {co0, co0+1}; transpose via [16][65]
  sred[(size_t)co0 * 65 + lane] = s[0];
  sred[(size_t)(co0 + 1) * 65 + lane] = s[1];
  sred[(size_t)(8 + co0) * 65 + lane] = q[0];
  sred[(size_t)(8 + co0 + 1) * 65 + lane] = q[1];
  __syncthreads();
  const int row = tid >> 4, seg = tid & 15;
  float p = sred[row * 65 + seg * 4] + sred[row * 65 + seg * 4 + 1] +
            sred[row * 65 + seg * 4 + 2] + sred[row * 65 + seg * 4 + 3];
  p += __shfl_down(p, 8, 64);
  p += __shfl_down(p, 4, 64);
  p += __shfl_down(p, 2, 64);
  p += __shfl_down(p, 1, 64);
  if (seg == 0) {
    const int cch = (row < 8) ? row : row - 8;
    const int slot = (row < 8) ? 2 * cch : 2 * cch + 1;
    unsafeAtomicAdd(st1 + (size_t)(blockIdx.x & 7) * 128 + (size_t)slot * 8,
                    (double)p);
  }
}

// xr1 = relu(bn1(y1)) stats; grid-strided NHWC streaming, grid 1024.
__global__ __launch_bounds__(256) void k_xr1_stats(
    const f16* __restrict__ y1, const float* __restrict__ g1,
    const float* __restrict__ b1, const double* __restrict__ st1,
    double* __restrict__ st2) {
  __shared__ float sred[16 * 257];
  __shared__ float sA[8], sC[8];
  if (threadIdx.x < 8) {
    const int c = threadIdx.x;
    double sd = 0.0, qd = 0.0;
#pragma unroll
    for (int b = 0; b < 8; ++b) {
      sd += STG(st1, b * 16 + 2 * c);
      qd += STG(st1, b * 16 + 2 * c + 1);
    }
    double md = sd / CNT1;
    float inv = (float)(1.0 / sqrt(qd / CNT1 - md * md + (double)EPS_BN));
    float a = inv * g1[c];
    sA[c] = a;
    sC[c] = b1[c] - (float)md * a;
  }
  __syncthreads();
  float a1[8], c1[8];
#pragma unroll
  for (int c = 0; c < 8; ++c) { a1[c] = sA[c]; c1[c] = sC[c]; }
  const size_t base = (size_t)blockIdx.x * 4096 + threadIdx.x;
  float s[8], q[8];
#pragma unroll
  for (int c = 0; c < 8; ++c) { s[c] = 0.f; q[c] = 0.f; }
#pragma unroll
  for (int k = 0; k < 16; ++k) {
    f16x8 v = *(const f16x8*)&y1[(base + (size_t)k * 256) * 8];
#pragma unroll
    for (int c = 0; c < 8; ++c) {
      float xr = fmaxf((float)v[c] * a1[c] + c1[c], 0.f);
      s[c] += xr; q[c] += xr * xr;
    }
  }
  block_stats_lds(s, q, sred, st2);
}

// ---------- FUSED: l1 epilogue + layer-2 conv via MFMA -----------------------
// Staging computes h1 values ON THE FLY from y1 (BN1+relu+scale+BN2+relu+pool)
// directly into conv2's padded LDS tile — h1 never touches HBM.
// 4 images/block, grid 1024.
// Writes y2 f16 channel-major [img][16co][256px] + stats (on rounded values).
__global__ __launch_bounds__(256) void k_conv2_fused(
    const f16* __restrict__ y1, const float* __restrict__ g1,
    const float* __restrict__ b1, const float* __restrict__ dsew,
    const float* __restrict__ bng, const float* __restrict__ bnb,
    const float* __restrict__ w2, const double* __restrict__ st1,
    const double* __restrict__ st2, f16* __restrict__ y2,
    double* __restrict__ st3) {
  __shared__ short smem[4 * 5184 + 10 * 256];
  __shared__ float red[4][32];
  __shared__ float cA1[8], cC1[8], cS2[16], cO2[16];
  short* hs = smem;                 // 4 padded images [18][18][16ch]
  short* wt = smem + 4 * 5184;      // [10][16co][16ci], slot 9 stays zero
  const int tid = threadIdx.x, wid = tid >> 6, lane = tid & 63;
  for (int i = tid; i < (4 * 5184 + 10 * 256) / 2; i += 256) ((int*)smem)[i] = 0;
  if (tid < 16) {  // l1 epilogue coefficients
    const int i = tid >> 1, g = tid & 1;
    double sd = 0.0, qd = 0.0;
#pragma unroll
    for (int b = 0; b < 8; ++b) {
      sd += STG(st1, b * 16 + 2 * i);
      qd += STG(st1, b * 16 + 2 * i + 1);
    }
    double md = sd / CNT1;
    float inv1 = (float)(1.0 / sqrt(qd / CNT1 - md * md + (double)EPS_BN));
    float a1 = inv1 * g1[i];
    if (g == 0) { cA1[i] = a1; cC1[i] = b1[i] - (float)md * a1; }
    double s2 = STG(st2, 2 * i), q2 = STG(st2, 2 * i + 1);
    double mx = s2 / CNT1, vx = q2 / CNT1 - mx * mx;
    float w = dsew[i * 2 + g];
    double inv2 = 1.0 / sqrt((double)w * w * vx + (double)EPS_BN);
    cS2[tid] = (float)(w * inv2) * bng[tid];
    cO2[tid] = bnb[tid] - (float)(w * mx * inv2) * bng[tid];
  }
  __syncthreads();
  for (int i = tid; i < 2304; i += 256) {
    const int s = i >> 8, co = (i >> 4) & 15, ci = i & 15;
    wt[i] = f2bf(w2[(co * 16 + ci) * 9 + s]);
  }
  const int c = lane & 15, quad = lane >> 4;
  const int ci0 = (quad & 1) * 8;
  int aoff[5];
#pragma unroll
  for (int p = 0; p < 5; ++p) {
    int s = 2 * p + (quad >> 1);
    if (s > 8) s = 8;  // address clamp; B-frag for that k-half is zero
    const int dy = s / 3, dx = s % 3;
    aoff[p] = (dy * 18 + (c + dx)) * 16 + ci0;
  }
  float ssum = 0.f, qsum = 0.f;
  const int n0 = blockIdx.x * 4;
  __syncthreads();  // wt staged; zero-init visible
  // stage 4 images: compute h1 from y1 + epilogue, write padded LDS tile.
  for (int e = tid; e < 2048; e += 256) {
    const int im = e >> 9, j = e & 511, px = j >> 1, half = j & 1;
    const int r = px >> 4, cx = px & 15;
    const size_t pb =
        ((size_t)(n0 + im) * 1024 + (size_t)(2 * r) * 32 + 2 * cx) * 8 +
        half * 4;
    f16x4 vA = *(const f16x4*)&y1[pb];        // (2r,   2cx)
    f16x4 vB = *(const f16x4*)&y1[pb + 8];    // (2r,   2cx+1)
    f16x4 vC = *(const f16x4*)&y1[pb + 256];  // (2r+1, 2cx)
    f16x4 vD = *(const f16x4*)&y1[pb + 264];  // (2r+1, 2cx+1)
    short hv[8];
#pragma unroll
    for (int ii = 0; ii < 4; ++ii) {
      const int i = half * 4 + ii;
      float a = cA1[i], cb = cC1[i];
      float x0 = fmaxf((float)vA[ii] * a + cb, 0.f);
      float x1 = fmaxf((float)vB[ii] * a + cb, 0.f);
      float x2 = fmaxf((float)vC[ii] * a + cb, 0.f);
      float x3 = fmaxf((float)vD[ii] * a + cb, 0.f);
#pragma unroll
      for (int g = 0; g < 2; ++g) {
        const int ch = 2 * i + g;
        float sc = cS2[ch], of = cO2[ch];
        float r0 = fmaxf(x0 * sc + of, 0.f);
        float r1 = fmaxf(x1 * sc + of, 0.f);
        float r2 = fmaxf(x2 * sc + of, 0.f);
        float r3 = fmaxf(x3 * sc + of, 0.f);
        hv[ii * 2 + g] = f2bf(fmaxf(fmaxf(r0, r1), fmaxf(r2, r3)));
      }
    }
    *(uint4*)&hs[im * 5184 + ((r + 1) * 18 + (cx + 1)) * 16 + half * 8] =
        *(uint4*)hv;
  }
  __syncthreads();
  bf16x8 bf[5];
#pragma unroll
  for (int p = 0; p < 5; ++p) {
    const int s = 2 * p + (quad >> 1);  // s==9 -> wt slot 9 == zeros
    bf[p] = *(const bf16x8*)&wt[s * 256 + c * 16 + ci0];
  }
  const short* hbase = hs + wid * 5184;
  const int img = n0 + wid;
  f16* yp = y2 + ((size_t)img * 16 + c) * 256 + quad * 4;
  for (int r = 0; r < 16; ++r) {
    f32x4 acc = {0.f, 0.f, 0.f, 0.f};
#pragma unroll
    for (int p = 0; p < 5; ++p) {
      bf16x8 a = *(const bf16x8*)&hbase[r * 288 + aoff[p]];
      acc = __builtin_amdgcn_mfma_f32_16x16x32_bf16(a, bf[p], acc, 0, 0, 0);
    }
    f16 hv[4];
#pragma unroll
    for (int g = 0; g < 4; ++g) {
      hv[g] = (f16)acc[g];
      float v = (float)hv[g];  // stats on rounded value (self-consistent)
      ssum += v; qsum += v * v;
    }
    *(f16x4*)&yp[r * 16] = *(f16x4*)hv;
  }
  // lanes {l, l+16, l+32, l+48} share co = l&15
  ssum += __shfl_down(ssum, 32, 64); ssum += __shfl_down(ssum, 16, 64);
  qsum += __shfl_down(qsum, 32, 64); qsum += __shfl_down(qsum, 16, 64);
  if (lane < 16) { red[wid][lane] = ssum; red[wid][16 + lane] = qsum; }
  __syncthreads();
  if (tid < 32) {
    const int cc2 = tid & 15, isq = tid >> 4;
    float v = red[0][isq * 16 + cc2] + red[1][isq * 16 + cc2] +
              red[2][isq * 16 + cc2] + red[3][isq * 16 + cc2];
    unsafeAtomicAdd(st3 + (size_t)(2 * cc2 + isq) * 8, (double)v);
  }
}

// xr2 = relu(bn3(y2)) stats; 8 images/block, 16B vector reads, grid 512.
__global__ __launch_bounds__(256) void k_xr2_stats(
    const f16* __restrict__ y2, const float* __restrict__ g2,
    const float* __restrict__ b2, const double* __restrict__ st3,
    double* __restrict__ st4) {
  __shared__ float red[32];
  const int tid = threadIdx.x, c = tid >> 4, seg = tid & 15;
  double sd = STG(st3, 2 * c), qd = STG(st3, 2 * c + 1);
  double md = sd / CNT2;
  float inv = (float)(1.0 / sqrt(qd / CNT2 - md * md + (double)EPS_BN));
  float a3 = inv * g2[c];
  float c3 = b2[c] - (float)md * a3;
  float s = 0.f, q = 0.f;
#pragma unroll
  for (int k = 0; k < 8; ++k) {
    const f16* p =
        &y2[(((size_t)(blockIdx.x * 8 + k)) * 16 + c) * 256 + seg * 16];
    f16x8 v0 = *(const f16x8*)p;
    f16x8 v1 = *(const f16x8*)(p + 8);
#pragma unroll
    for (int j = 0; j < 8; ++j) {
      float x0 = fmaxf((float)v0[j] * a3 + c3, 0.f);
      float x1 = fmaxf((float)v1[j] * a3 + c3, 0.f);
      s += x0 + x1; q += x0 * x0 + x1 * x1;
    }
  }
#pragma unroll
  for (int o = 8; o > 0; o >>= 1) {
    s += __shfl_down(s, o, 64);
    q += __shfl_down(q, o, 64);
  }
  if ((tid & 15) == 0) { red[2 * c] = s; red[2 * c + 1] = q; }
  __syncthreads();
  if (tid < 32) unsafeAtomicAdd(st4 + (size_t)tid * 8, (double)red[tid]);
}

// y2 f16 -> BN+relu -> scale-expand -> BN+relu -> 2x2 maxpool -> h2 bf16
__global__ __launch_bounds__(256) void k_l2_out(
    const f16* __restrict__ y2, const float* __restrict__ g2,
    const float* __restrict__ b2, const float* __restrict__ dsew,
    const float* __restrict__ bng, const float* __restrict__ bnb,
    const double* __restrict__ st3, const double* __restrict__ st4,
    short* __restrict__ h2) {
  __shared__ float cS3[16], cO3[16], cS4[32], cO4[32];
  const int tid = threadIdx.x;
  if (tid < 32) {
    const int i = tid >> 1, g = tid & 1;
    double sd = STG(st3, 2 * i), qd = STG(st3, 2 * i + 1);
    double md = sd / CNT2;
    float inv3 = (float)(1.0 / sqrt(qd / CNT2 - md * md + (double)EPS_BN));
    float a3 = inv3 * g2[i];
    if (g == 0) { cS3[i] = a3; cO3[i] = b2[i] - (float)md * a3; }
    double s4 = STG(st4, 2 * i), q4 = STG(st4, 2 * i + 1);
    double mx = s4 / CNT2, vx = q4 / CNT2 - mx * mx;
    float w = dsew[2 * i + g];
    double inv4 = 1.0 / sqrt((double)w * w * vx + (double)EPS_BN);
    cS4[tid] = (float)(w * inv4) * bng[tid];
    cO4[tid] = bnb[tid] - (float)(w * mx * inv4) * bng[tid];
  }
  __syncthreads();
  const int sub = tid >> 6, lane = tid & 63;
  const int n = blockIdx.x * 4 + sub;
  const int px = lane & 7, py = lane >> 3;
#pragma unroll
  for (int i = 0; i < 16; ++i) {
    const size_t base = ((size_t)n * 16 + i) * 256;
    f16x2 v01 = *(const f16x2*)&y2[base + (2 * py) * 16 + 2 * px];
    f16x2 v23 = *(const f16x2*)&y2[base + (2 * py + 1) * 16 + 2 * px];
    float a3 = cS3[i], c3 = cO3[i];
    float xr0 = fmaxf((float)v01[0] * a3 + c3, 0.f);
    float xr1 = fmaxf((float)v01[1] * a3 + c3, 0.f);
    float xr2 = fmaxf((float)v23[0] * a3 + c3, 0.f);
    float xr3 = fmaxf((float)v23[1] * a3 + c3, 0.f);
#pragma unroll
    for (int g = 0; g < 2; ++g) {
      const int c = 2 * i + g;
      float sc = cS4[c], of = cO4[c];
      float r0 = fmaxf(xr0 * sc + of, 0.f);
      float r1 = fmaxf(xr1 * sc + of, 0.f);
      float r2 = fmaxf(xr2 * sc + of, 0.f);
      float r3 = fmaxf(xr3 * sc + of, 0.f);
      h2[(size_t)n * 2048 + c * 64 + py * 8 + px] =
          f2bf(fmaxf(fmaxf(r0, r1), fmaxf(r2, r3)));
    }
  }
}

// cast fc1_w/fc2_w to bf16 (vectorized) + zero stat slots + conv1 wT table
__global__ __launch_bounds__(256) void k_cast_w(const float* __restrict__ w1,
                                                const float* __restrict__ w2,
                                                const float* __restrict__ dfe1,
                                                short* __restrict__ o1,
                                                short* __restrict__ o2,
                                                double* __restrict__ st,
                                                float* __restrict__ wt) {
  const int i4 = blockIdx.x * 256 + threadIdx.x;
  if (blockIdx.x == 0) {
    for (int k = threadIdx.x; k < 1664; k += 256) st[k] = 0.0;
    if (threadIdx.x < 216)
      wt[(threadIdx.x % 27) * 8 + threadIdx.x / 27] = dfe1[threadIdx.x];
  }
  if (i4 < 262144) {
    float4 v = ((const float4*)w1)[i4];
    short h[4] = {f2bf(v.x), f2bf(v.y), f2bf(v.z), f2bf(v.w)};
    ((uint2*)o1)[i4] = *(uint2*)h;
  } else if (i4 < 327680) {
    const int j = i4 - 262144;
    float4 v = ((const float4*)w2)[j];
    short h[4] = {f2bf(v.x), f2bf(v.y), f2bf(v.z), f2bf(v.w)};
    ((uint2*)o2)[j] = *(uint2*)h;
  }
}

// ------------- FC via LDS-staged MFMA GEMM ----------------------------------
// C[M,512] = act(A[M,K]bf16 @ W[512,K]bf16^T + b)
// block 64x64, BK=64, 4 waves (wave = 16 rows x 64 cols, 4 accs),
// double-buffered LDS staged via global_load_lds(16B).
// Swizzle (G21 both-sides): LDS linear dest; SOURCE col-seg XOR row&7;
// ds_read applies same XOR -> conflict-free 8-lane groups.
// XCD swizzle: 8 col-blocks of one row-strip -> same XCD (A-strip+W = 4MB=L2).
template <int K, int RELU, int OUT_BF16>
__global__ __launch_bounds__(256) void k_fc_lds(
    const short* __restrict__ A, const short* __restrict__ W,
    const float* __restrict__ bias, void* __restrict__ Cv) {
  // [buf][0:A|1:B][64 rows][64 shorts] = 32 KiB
  __shared__ __align__(16) short lds[2][2][64 * 64];
  const int tid = threadIdx.x, w = tid >> 6, lane = tid & 63;
  // grid (8,64); remap so xcd (= linear id % 8) == row-strip & 7
  const int id = blockIdx.y * 8 + blockIdx.x;
  const int bx = (id >> 3) & 7;
  const int by = ((id >> 6) << 3) | (id & 7);
  const int bm = by * 64, bn = bx * 64;
  const int cl = lane & 15, quad = lane >> 4;
  const int srow = lane >> 3, sseg = lane & 7;  // staging: 8 rows x 8 segs
  // wave w stages A rows / B cols [w*16 + j*8 .. +8), j=0,1.
  // source seg = sseg ^ (row&7) = sseg ^ srow (row strips are 8-aligned).
  const size_t soff = (size_t)srow * K + ((size_t)(sseg ^ srow) << 3);
  const short* aS0 = A + (size_t)(bm + w * 16) * K + soff;
  const short* aS1 = A + (size_t)(bm + w * 16 + 8) * K + soff;
  const short* bS0 = W + (size_t)(bn + w * 16) * K + soff;
  const short* bS1 = W + (size_t)(bn + w * 16 + 8) * K + soff;

#define GLD16(src, dst)                                                    \
  __builtin_amdgcn_global_load_lds(                                        \
      (const __attribute__((address_space(1))) void*)(const void*)(src),   \
      (__attribute__((address_space(3))) void*)(void*)(dst), 16, 0, 0)
#define STAGE(buf, k0)                                               \
  do {                                                               \
    GLD16(aS0 + (k0), &lds[buf][0][(w * 16) * 64]);                  \
    GLD16(aS1 + (k0), &lds[buf][0][(w * 16 + 8) * 64]);              \
    GLD16(bS0 + (k0), &lds[buf][1][(w * 16) * 64]);                  \
    GLD16(bS1 + (k0), &lds[buf][1][(w * 16 + 8) * 64]);              \
  } while (0)

  f32x4 acc[4];
#pragma unroll
  for (int ct = 0; ct < 4; ++ct) acc[ct] = (f32x4){0.f, 0.f, 0.f, 0.f};
  // frag read offsets (shorts), within A/B section
  int aOff[2], bOff0[2];
#pragma unroll
  for (int kk = 0; kk < 2; ++kk) {
    const int sw = ((kk * 4 + quad) ^ (cl & 7)) << 3;
    aOff[kk] = (w * 16 + cl) * 64 + sw;
    bOff0[kk] = cl * 64 + sw;  // + ct*16*64 per col-tile
  }
  constexpr int NT = K / 64;
  STAGE(0, 0);
#pragma unroll 2
  for (int t = 0; t < NT; ++t) {
    asm volatile("s_waitcnt vmcnt(0)" ::: "memory");
    __syncthreads();
    if (t + 1 < NT) STAGE((t + 1) & 1, (t + 1) * 64);
    const short* As = &lds[t & 1][0][0];
    const short* Bs = &lds[t & 1][1][0];
#pragma unroll
    for (int kk = 0; kk < 2; ++kk) {
      bf16x8 a = *(const bf16x8*)&As[aOff[kk]];
#pragma unroll
      for (int ct = 0; ct < 4; ++ct) {
        bf16x8 b = *(const bf16x8*)&Bs[bOff0[kk] + ct * 1024];
        acc[ct] = __builtin_amdgcn_mfma_f32_16x16x32_bf16(a, b, acc[ct], 0, 0, 0);
      }
    }
  }
#undef STAGE
#undef GLD16
#pragma unroll
  for (int ct = 0; ct < 4; ++ct) {
    const int col = bn + ct * 16 + cl;
    const float bia = bias[col];
#pragma unroll
    for (int r = 0; r < 4; ++r) {
      const int row = bm + w * 16 + quad * 4 + r;
      float v = acc[ct][r] + bia;
      if (RELU) v = fmaxf(v, 0.f);
      if (OUT_BF16)
        ((short*)Cv)[(size_t)row * 512 + col] = f2bf(v);
      else
        ((float*)Cv)[(size_t)row * 512 + col] = v;
    }
  }
}

// fc3: one wave per row, N=10, K=512, fp32
__global__ __launch_bounds__(256) void k_fc3(const float* __restrict__ A,
                                             const float* __restrict__ W,
                                             const float* __restrict__ b,
                                             float* __restrict__ out) {
  const int wid = threadIdx.x >> 6, lane = threadIdx.x & 63;
  const int row = blockIdx.x * 4 + wid;
  float p[10];
#pragma unroll
  for (int o = 0; o < 10; ++o) p[o] = 0.f;
  const float* a = A + (size_t)row * 512;
#pragma unroll
  for (int jj = 0; jj < 8; ++jj) {
    const int j = lane + jj * 64;
    float av = a[j];
#pragma unroll
    for (int o = 0; o < 10; ++o) p[o] += av * W[o * 512 + j];
  }
#pragma unroll
  for (int o = 0; o < 10; ++o) p[o] = wave_sum(p[o]);
  if (lane == 0) {
#pragma unroll
    for (int o = 0; o < 10; ++o) out[(size_t)row * 10 + o] = p[o] + b[o];
  }
}

}  // namespace

extern "C" void kernel_launch(void* const* d_in, const int* in_sizes, int n_in,
                              void* d_out, int out_size, void* d_ws,
                              size_t ws_size, hipStream_t stream) {
  const float* x      = (const float*)d_in[0];
  const float* dfe1_w = (const float*)d_in[1];
  const float* dse1_g = (const float*)d_in[2];
  const float* dse1_b = (const float*)d_in[3];
  const float* dse1_w = (const float*)d_in[4];
  const float* bn1_g  = (const float*)d_in[5];
  const float* bn1_b  = (const float*)d_in[6];
  const float* dfe2_w = (const float*)d_in[7];
  const float* dse2_g = (const float*)d_in[8];
  const float* dse2_b = (const float*)d_in[9];
  const float* dse2_w = (const float*)d_in[10];
  const float* bn2_g  = (const float*)d_in[11];
  const float* bn2_b  = (const float*)d_in[12];
  const float* fc1_w  = (const float*)d_in[13];
  const float* fc1_b  = (const float*)d_in[14];
  const float* fc2_w  = (const float*)d_in[15];
  const float* fc2_b  = (const float*)d_in[16];
  const float* fc3_w  = (const float*)d_in[17];
  const float* fc3_b  = (const float*)d_in[18];
  float* out = (float*)d_out;
  char* ws = (char*)d_ws;
  f16* y1 = (f16*)(ws + OFF_Y1);
  f16* y2 = (f16*)(ws + OFF_Y2);
  short* h2 = (short*)(ws + OFF_H2);
  short* a1 = (short*)(ws + OFF_A1);
  float* a2 = (float*)(ws + OFF_A2);
  short* wb1 = (short*)(ws + OFF_WB1);
  short* wb2 = (short*)(ws + OFF_WB2);
  float* wt1 = (float*)(ws + OFF_WT);
  double* st = (double*)(ws + OFF_ST);
  double* ST1 = st;                       // 128 slots: 8 banks x 16
  double* ST2 = st + (size_t)128 * 8;     // 16 slots
  double* ST3 = st + (size_t)144 * 8;     // 32 slots
  double* ST4 = st + (size_t)176 * 8;     // 32 slots

  k_cast_w<<<1280, 256, 0, stream>>>(fc1_w, fc2_w, dfe1_w, wb1, wb2, st, wt1);
  k_conv1_y1<<<2048, 256, 0, stream>>>(x, wt1, y1, ST1);
  k_xr1_stats<<<1024, 256, 0, stream>>>(y1, dse1_g, dse1_b, ST1, ST2);
  k_conv2_fused<<<1024, 256, 0, stream>>>(y1, dse1_g, dse1_b, dse1_w, bn1_g,
                                          bn1_b, dfe2_w, ST1, ST2, y2, ST3);
  k_xr2_stats<<<512, 256, 0, stream>>>(y2, dse2_g, dse2_b, ST3, ST4);
  k_l2_out<<<1024, 256, 0, stream>>>(y2, dse2_g, dse2_b, dse2_w, bn2_g, bn2_b,
                                     ST3, ST4, h2);
  k_fc_lds<2048, 1, 1><<<dim3(8, 64), 256, 0, stream>>>(h2, wb1, fc1_b, a1);
  k_fc_lds<512, 1, 0><<<dim3(8, 64), 256, 0, stream>>>(a1, wb2, fc2_b, a2);
  k_fc3<<<1024, 256, 0, stream>>>(a2, fc3_w, fc3_b, out);
}

// Round 13
// 282.940 us; speedup vs baseline: 1.0448x; 1.0448x over previous
//
#include <hip/hip_runtime.h>
#include <math.h>

#define EPS_BN 1e-5

namespace {

constexpr double CNT1 = 4096.0 * 1024.0;  // layer1 BN count: B*32*32
constexpr double CNT2 = 4096.0 * 256.0;   // layer2 BN count: B*16*16

// workspace layout (bytes). Required ws >= ~131 MiB.
constexpr size_t OFF_Y1 = 0;            // [4096,1024px,8ch] f16 = 64 MiB (live thru conv2)
constexpr size_t OFF_Y2 = 67108864;     // [4096,16ch,256px] f16 = 32 MiB
constexpr size_t OFF_H2 = 100663296;    // [4096,2048] bf16 = 16 MiB
constexpr size_t OFF_A1 = 117440512;    // [4096,512] bf16 = 4 MiB
constexpr size_t OFF_A2 = 121634816;    // [4096,512] f32 = 8 MiB
constexpr size_t OFF_ST = 134217728;    // BN stats: 208 slots x 64B (13312 B)
constexpr size_t OFF_WT = 134234112;    // conv1 weights transposed [27][8] f32 (in ST region slack)
constexpr size_t OFF_WB1 = 134283264;   // fc1_w bf16 [512,2048] = 2 MiB
constexpr size_t OFF_WB2 = 136380416;   // fc2_w bf16 [512,512] = 0.5 MiB

#define STG(p, i) (p)[(size_t)(i) * 8]

typedef short bf16x8 __attribute__((ext_vector_type(8)));
typedef float f32x4 __attribute__((ext_vector_type(4)));
typedef _Float16 f16;
typedef _Float16 f16x2 __attribute__((ext_vector_type(2)));
typedef _Float16 f16x4 __attribute__((ext_vector_type(4)));
typedef _Float16 f16x8 __attribute__((ext_vector_type(8)));

__device__ __forceinline__ short f2bf(float f) {
  unsigned u = __float_as_uint(f);
  u = (u + 0x7fffu + ((u >> 16) & 1u)) >> 16;
  return (short)u;
}

// LDS-transpose block stats for 8 channels (s+q = 16 values/thread).
// sred must be >= 16*257 floats, untouched before the call.
// Atomic slot layout: STG slot 2c = s[c], 2c+1 = q[c].
__device__ __forceinline__ void block_stats_lds(const float* s, const float* q,
                                                float* __restrict__ sred,
                                                double* __restrict__ st) {
  const int tid = threadIdx.x;
#pragma unroll
  for (int j = 0; j < 8; ++j) {
    sred[j * 257 + tid] = s[j];        // bank = (j + tid)%32: conflict-free
    sred[(j + 8) * 257 + tid] = q[j];
  }
  __syncthreads();
  const int row = tid >> 4, seg = tid & 15;  // row = stat idx 0..15
  float p = 0.f;
#pragma unroll
  for (int k = 0; k < 16; ++k) {
    const int ke = (k + seg) & 15;  // swizzle to spread banks
    p += sred[row * 257 + seg * 16 + ke];
  }
  p += __shfl_down(p, 8, 64);
  p += __shfl_down(p, 4, 64);
  p += __shfl_down(p, 2, 64);
  p += __shfl_down(p, 1, 64);
  if (seg == 0) {
    const int c = (row < 8) ? row : row - 8;
    const int slot = (row < 8) ? 2 * c : 2 * c + 1;
    unsafeAtomicAdd(st + (size_t)slot * 8, (double)p);
  }
}

__device__ __forceinline__ float wave_sum(float v) {
#pragma unroll
  for (int o = 32; o > 0; o >>= 1) v += __shfl_down(v, o, 64);
  return v;
}

// ---------------- layer 1: conv 3x3, 3->8, on 32x32, pad 1 -------------------
// R20 "co-split" (REVERTED to R11-measured-best: 61us, VALUBusy 37, occ 48).
// R12's direct-load variant regressed (67us, VGPR 52): the 9 scattered vmem
// loads/step cost more than the 6 shuffles they replaced. Six structural
// variants all land 61-75us -> conv1 parked at its practical local minimum;
// pivoting effort elsewhere (R13: conv2_fused occupancy).
// thread = full column x co-PAIR; wave = wave-uniform co-pair g, 2 images x
// 32 cols; block = 4 waves = 2 images; grid 2048. 54 weights hoisted to
// SGPRs once; main loop: 54 v_fmac + 3 global loads + 6 shuffles per step,
// zero LDS, zero barriers. 3-phase static acc rotation.
// Stats 8-sub-banked by blockIdx&7. Writes y1 f16 NHWC [n][1024px][8ch].
__global__ __launch_bounds__(256) void k_conv1_y1(
    const float* __restrict__ x, const float* __restrict__ wt,
    f16* __restrict__ y1, double* __restrict__ st1) {
  __shared__ float sred[16 * 65];  // 4.2 KB stats transpose
  const int tid = threadIdx.x;
  const int g = __builtin_amdgcn_readfirstlane(tid >> 6);  // co-pair 0..3
  const int lane = tid & 63;
  const int img = lane >> 5, c = lane & 31;
  const int n = blockIdx.x * 2 + img;
  const int co0 = 2 * g;
  const float* xp = x + (size_t)n * 3072 + c;  // [3][32][32], this column
  f16* yp = y1 + (size_t)n * 8192;
  // hoist this wave's 54 weights (wave-uniform addr -> s_load, resident)
  float wA[27], wB[27];
#pragma unroll
  for (int t = 0; t < 27; ++t) {
    wA[t] = wt[t * 8 + co0];
    wB[t] = wt[t * 8 + co0 + 1];
  }
  float a0[2], a1[2], a2[2], s[2], q[2];
#pragma unroll
  for (int j = 0; j < 2; ++j) {
    a0[j] = 0.f; a1[j] = 0.f; a2[j] = 0.f; s[j] = 0.f; q[j] = 0.f;
  }
  float xM[3];
  xM[0] = xp[0]; xM[1] = xp[1024]; xM[2] = xp[2048];  // row 0

#define CONTRIB(ACC, T, XV)                                           \
  {                                                                   \
    ACC[0] += wA[T] * (XV);                                           \
    ACC[1] += wB[T] * (XV);                                           \
  }

  // STEP(R): consume x-row R (in xM), prefetch row R+1, complete y-row R-1.
  // AP = y[R-1], AC = y[R], AN = y[R+1].
#define STEP(R, AP, AC, AN)                                           \
  {                                                                   \
    float nM0 = 0.f, nM1 = 0.f, nM2 = 0.f;                            \
    if ((R) <= 30) {                                                  \
      const float* rp = xp + ((R) + 1) * 32;                          \
      nM0 = rp[0]; nM1 = rp[1024]; nM2 = rp[2048];                    \
    }                                                                 \
    _Pragma("unroll") for (int ci = 0; ci < 3; ++ci) {                \
      const float xm = xM[ci];                                        \
      float xl = __shfl_up(xm, 1, 64);                                \
      float xr = __shfl_down(xm, 1, 64);                              \
      if (c == 0) xl = 0.f;                                           \
      if (c == 31) xr = 0.f;                                          \
      CONTRIB(AN, ci * 9 + 0, xl);                                    \
      CONTRIB(AN, ci * 9 + 1, xm);                                    \
      CONTRIB(AN, ci * 9 + 2, xr);                                    \
      CONTRIB(AC, ci * 9 + 3, xl);                                    \
      CONTRIB(AC, ci * 9 + 4, xm);                                    \
      CONTRIB(AC, ci * 9 + 5, xr);                                    \
      CONTRIB(AP, ci * 9 + 6, xl);                                    \
      CONTRIB(AP, ci * 9 + 7, xm);                                    \
      CONTRIB(AP, ci * 9 + 8, xr);                                    \
    }                                                                 \
    if ((R) >= 1) {                                                   \
      float v0 = AP[0], v1 = AP[1];                                   \
      s[0] += v0; q[0] += v0 * v0;                                    \
      s[1] += v1; q[1] += v1 * v1;                                    \
      f16 hv[2] = {(f16)v0, (f16)v1};                                 \
      *(unsigned*)&yp[(size_t)((R) - 1) * 256 + c * 8 + co0] =        \
          *(unsigned*)hv;                                             \
    }                                                                 \
    AP[0] = 0.f; AP[1] = 0.f;                                         \
    xM[0] = nM0; xM[1] = nM1; xM[2] = nM2;                            \
  }

  for (int rb = 0; rb < 33; rb += 3) {
    STEP(rb,     a2, a0, a1);  // R%3==0: y[R-1]->a2, y[R]->a0, y[R+1]->a1
    STEP(rb + 1, a0, a1, a2);
    STEP(rb + 2, a1, a2, a0);
  }
#undef STEP
#undef CONTRIB
  // stats: each thread holds s,q for co {co0, co0+1}; transpose via [16][65]
  sred[(size_t)co0 * 65 + lane] = s[0];
  sred[(size_t)(co0 + 1) * 65 + lane] = s[1];
  sred[(size_t)(8 + co0) * 65 + lane] = q[0];
  sred[(size_t)(8 + co0 + 1) * 65 + lane] = q[1];
  __syncthreads();
  const int row = tid >> 4, seg = tid & 15;
  float p = sred[row * 65 + seg * 4] + sred[row * 65 + seg * 4 + 1] +
            sred[row * 65 + seg * 4 + 2] + sred[row * 65 + seg * 4 + 3];
  p += __shfl_down(p, 8, 64);
  p += __shfl_down(p, 4, 64);
  p += __shfl_down(p, 2, 64);
  p += __shfl_down(p, 1, 64);
  if (seg == 0) {
    const int cch = (row < 8) ? row : row - 8;
    const int slot = (row < 8) ? 2 * cch : 2 * cch + 1;
    unsafeAtomicAdd(st1 + (size_t)(blockIdx.x & 7) * 128 + (size_t)slot * 8,
                    (double)p);
  }
}

// xr1 = relu(bn1(y1)) stats; grid-strided NHWC streaming, grid 1024.
__global__ __launch_bounds__(256) void k_xr1_stats(
    const f16* __restrict__ y1, const float* __restrict__ g1,
    const float* __restrict__ b1, const double* __restrict__ st1,
    double* __restrict__ st2) {
  __shared__ float sred[16 * 257];
  __shared__ float sA[8], sC[8];
  if (threadIdx.x < 8) {
    const int c = threadIdx.x;
    double sd = 0.0, qd = 0.0;
#pragma unroll
    for (int b = 0; b < 8; ++b) {
      sd += STG(st1, b * 16 + 2 * c);
      qd += STG(st1, b * 16 + 2 * c + 1);
    }
    double md = sd / CNT1;
    float inv = (float)(1.0 / sqrt(qd / CNT1 - md * md + (double)EPS_BN));
    float a = inv * g1[c];
    sA[c] = a;
    sC[c] = b1[c] - (float)md * a;
  }
  __syncthreads();
  float a1[8], c1[8];
#pragma unroll
  for (int c = 0; c < 8; ++c) { a1[c] = sA[c]; c1[c] = sC[c]; }
  const size_t base = (size_t)blockIdx.x * 4096 + threadIdx.x;
  float s[8], q[8];
#pragma unroll
  for (int c = 0; c < 8; ++c) { s[c] = 0.f; q[c] = 0.f; }
#pragma unroll
  for (int k = 0; k < 16; ++k) {
    f16x8 v = *(const f16x8*)&y1[(base + (size_t)k * 256) * 8];
#pragma unroll
    for (int c = 0; c < 8; ++c) {
      float xr = fmaxf((float)v[c] * a1[c] + c1[c], 0.f);
      s[c] += xr; q[c] += xr * xr;
    }
  }
  block_stats_lds(s, q, sred, st2);
}

// ---------- FUSED: l1 epilogue + layer-2 conv via MFMA -----------------------
// Staging computes h1 values ON THE FLY from y1 (BN1+relu+scale+BN2+relu+pool)
// directly into conv2's padded LDS tile — h1 never touches HBM.
// R13: 512 threads / 8 waves, 2 waves per image (row-halves rh*8..rh*8+7).
// Same 46.6 KB LDS -> 3 blocks/CU but 24 waves/CU (was 12, 37%): conv2 is
// the estimated #2 kernel (~45-55us hidden below conv1 in top-5) with the
// same low-occupancy signature conv1 had. Staging spreads 2048 elements
// over 512 threads; per-wave MFMA chain halves (80 -> 40).
// Writes y2 f16 channel-major [img][16co][256px] + stats (on rounded values).
__global__ __launch_bounds__(512) void k_conv2_fused(
    const f16* __restrict__ y1, const float* __restrict__ g1,
    const float* __restrict__ b1, const float* __restrict__ dsew,
    const float* __restrict__ bng, const float* __restrict__ bnb,
    const float* __restrict__ w2, const double* __restrict__ st1,
    const double* __restrict__ st2, f16* __restrict__ y2,
    double* __restrict__ st3) {
  __shared__ short smem[4 * 5184 + 10 * 256];
  __shared__ float red[8][32];
  __shared__ float cA1[8], cC1[8], cS2[16], cO2[16];
  short* hs = smem;                 // 4 padded images [18][18][16ch]
  short* wt = smem + 4 * 5184;      // [10][16co][16ci], slot 9 stays zero
  const int tid = threadIdx.x, wid = tid >> 6, lane = tid & 63;
  const int imw = wid >> 1, rh = wid & 1;  // image 0..3, row-half 0..1
  for (int i = tid; i < (4 * 5184 + 10 * 256) / 2; i += 512) ((int*)smem)[i] = 0;
  if (tid < 16) {  // l1 epilogue coefficients
    const int i = tid >> 1, g = tid & 1;
    double sd = 0.0, qd = 0.0;
#pragma unroll
    for (int b = 0; b < 8; ++b) {
      sd += STG(st1, b * 16 + 2 * i);
      qd += STG(st1, b * 16 + 2 * i + 1);
    }
    double md = sd / CNT1;
    float inv1 = (float)(1.0 / sqrt(qd / CNT1 - md * md + (double)EPS_BN));
    float a1 = inv1 * g1[i];
    if (g == 0) { cA1[i] = a1; cC1[i] = b1[i] - (float)md * a1; }
    double s2 = STG(st2, 2 * i), q2 = STG(st2, 2 * i + 1);
    double mx = s2 / CNT1, vx = q2 / CNT1 - mx * mx;
    float w = dsew[i * 2 + g];
    double inv2 = 1.0 / sqrt((double)w * w * vx + (double)EPS_BN);
    cS2[tid] = (float)(w * inv2) * bng[tid];
    cO2[tid] = bnb[tid] - (float)(w * mx * inv2) * bng[tid];
  }
  __syncthreads();
  for (int i = tid; i < 2304; i += 512) {
    const int s = i >> 8, co = (i >> 4) & 15, ci = i & 15;
    wt[i] = f2bf(w2[(co * 16 + ci) * 9 + s]);
  }
  const int c = lane & 15, quad = lane >> 4;
  const int ci0 = (quad & 1) * 8;
  int aoff[5];
#pragma unroll
  for (int p = 0; p < 5; ++p) {
    int s = 2 * p + (quad >> 1);
    if (s > 8) s = 8;  // address clamp; B-frag for that k-half is zero
    const int dy = s / 3, dx = s % 3;
    aoff[p] = (dy * 18 + (c + dx)) * 16 + ci0;
  }
  float ssum = 0.f, qsum = 0.f;
  const int n0 = blockIdx.x * 4;
  __syncthreads();  // wt staged; zero-init visible
  // stage 4 images: compute h1 from y1 + epilogue, write padded LDS tile.
  for (int e = tid; e < 2048; e += 512) {
    const int im = e >> 9, j = e & 511, px = j >> 1, half = j & 1;
    const int r = px >> 4, cx = px & 15;
    const size_t pb =
        ((size_t)(n0 + im) * 1024 + (size_t)(2 * r) * 32 + 2 * cx) * 8 +
        half * 4;
    f16x4 vA = *(const f16x4*)&y1[pb];        // (2r,   2cx)
    f16x4 vB = *(const f16x4*)&y1[pb + 8];    // (2r,   2cx+1)
    f16x4 vC = *(const f16x4*)&y1[pb + 256];  // (2r+1, 2cx)
    f16x4 vD = *(const f16x4*)&y1[pb + 264];  // (2r+1, 2cx+1)
    short hv[8];
#pragma unroll
    for (int ii = 0; ii < 4; ++ii) {
      const int i = half * 4 + ii;
      float a = cA1[i], cb = cC1[i];
      float x0 = fmaxf((float)vA[ii] * a + cb, 0.f);
      float x1 = fmaxf((float)vB[ii] * a + cb, 0.f);
      float x2 = fmaxf((float)vC[ii] * a + cb, 0.f);
      float x3 = fmaxf((float)vD[ii] * a + cb, 0.f);
#pragma unroll
      for (int g = 0; g < 2; ++g) {
        const int ch = 2 * i + g;
        float sc = cS2[ch], of = cO2[ch];
        float r0 = fmaxf(x0 * sc + of, 0.f);
        float r1 = fmaxf(x1 * sc + of, 0.f);
        float r2 = fmaxf(x2 * sc + of, 0.f);
        float r3 = fmaxf(x3 * sc + of, 0.f);
        hv[ii * 2 + g] = f2bf(fmaxf(fmaxf(r0, r1), fmaxf(r2, r3)));
      }
    }
    *(uint4*)&hs[im * 5184 + ((r + 1) * 18 + (cx + 1)) * 16 + half * 8] =
        *(uint4*)hv;
  }
  __syncthreads();
  bf16x8 bf[5];
#pragma unroll
  for (int p = 0; p < 5; ++p) {
    const int s = 2 * p + (quad >> 1);  // s==9 -> wt slot 9 == zeros
    bf[p] = *(const bf16x8*)&wt[s * 256 + c * 16 + ci0];
  }
  const short* hbase = hs + imw * 5184;
  const int img = n0 + imw;
  f16* yp = y2 + ((size_t)img * 16 + c) * 256 + quad * 4;
  for (int r = rh * 8; r < rh * 8 + 8; ++r) {
    f32x4 acc = {0.f, 0.f, 0.f, 0.f};
#pragma unroll
    for (int p = 0; p < 5; ++p) {
      bf16x8 a = *(const bf16x8*)&hbase[r * 288 + aoff[p]];
      acc = __builtin_amdgcn_mfma_f32_16x16x32_bf16(a, bf[p], acc, 0, 0, 0);
    }
    f16 hv[4];
#pragma unroll
    for (int g = 0; g < 4; ++g) {
      hv[g] = (f16)acc[g];
      float v = (float)hv[g];  // stats on rounded value (self-consistent)
      ssum += v; qsum += v * v;
    }
    *(f16x4*)&yp[r * 16] = *(f16x4*)hv;
  }
  // lanes {l, l+16, l+32, l+48} share co = l&15
  ssum += __shfl_down(ssum, 32, 64); ssum += __shfl_down(ssum, 16, 64);
  qsum += __shfl_down(qsum, 32, 64); qsum += __shfl_down(qsum, 16, 64);
  if (lane < 16) { red[wid][lane] = ssum; red[wid][16 + lane] = qsum; }
  __syncthreads();
  if (tid < 32) {
    const int cc2 = tid & 15, isq = tid >> 4;
    float v = 0.f;
#pragma unroll
    for (int wq = 0; wq < 8; ++wq) v += red[wq][isq * 16 + cc2];
    unsafeAtomicAdd(st3 + (size_t)(2 * cc2 + isq) * 8, (double)v);
  }
}

// xr2 = relu(bn3(y2)) stats; 8 images/block, 16B vector reads, grid 512.
__global__ __launch_bounds__(256) void k_xr2_stats(
    const f16* __restrict__ y2, const float* __restrict__ g2,
    const float* __restrict__ b2, const double* __restrict__ st3,
    double* __restrict__ st4) {
  __shared__ float red[32];
  const int tid = threadIdx.x, c = tid >> 4, seg = tid & 15;
  double sd = STG(st3, 2 * c), qd = STG(st3, 2 * c + 1);
  double md = sd / CNT2;
  float inv = (float)(1.0 / sqrt(qd / CNT2 - md * md + (double)EPS_BN));
  float a3 = inv * g2[c];
  float c3 = b2[c] - (float)md * a3;
  float s = 0.f, q = 0.f;
#pragma unroll
  for (int k = 0; k < 8; ++k) {
    const f16* p =
        &y2[(((size_t)(blockIdx.x * 8 + k)) * 16 + c) * 256 + seg * 16];
    f16x8 v0 = *(const f16x8*)p;
    f16x8 v1 = *(const f16x8*)(p + 8);
#pragma unroll
    for (int j = 0; j < 8; ++j) {
      float x0 = fmaxf((float)v0[j] * a3 + c3, 0.f);
      float x1 = fmaxf((float)v1[j] * a3 + c3, 0.f);
      s += x0 + x1; q += x0 * x0 + x1 * x1;
    }
  }
#pragma unroll
  for (int o = 8; o > 0; o >>= 1) {
    s += __shfl_down(s, o, 64);
    q += __shfl_down(q, o, 64);
  }
  if ((tid & 15) == 0) { red[2 * c] = s; red[2 * c + 1] = q; }
  __syncthreads();
  if (tid < 32) unsafeAtomicAdd(st4 + (size_t)tid * 8, (double)red[tid]);
}

// y2 f16 -> BN+relu -> scale-expand -> BN+relu -> 2x2 maxpool -> h2 bf16
__global__ __launch_bounds__(256) void k_l2_out(
    const f16* __restrict__ y2, const float* __restrict__ g2,
    const float* __restrict__ b2, const float* __restrict__ dsew,
    const float* __restrict__ bng, const float* __restrict__ bnb,
    const double* __restrict__ st3, const double* __restrict__ st4,
    short* __restrict__ h2) {
  __shared__ float cS3[16], cO3[16], cS4[32], cO4[32];
  const int tid = threadIdx.x;
  if (tid < 32) {
    const int i = tid >> 1, g = tid & 1;
    double sd = STG(st3, 2 * i), qd = STG(st3, 2 * i + 1);
    double md = sd / CNT2;
    float inv3 = (float)(1.0 / sqrt(qd / CNT2 - md * md + (double)EPS_BN));
    float a3 = inv3 * g2[i];
    if (g == 0) { cS3[i] = a3; cO3[i] = b2[i] - (float)md * a3; }
    double s4 = STG(st4, 2 * i), q4 = STG(st4, 2 * i + 1);
    double mx = s4 / CNT2, vx = q4 / CNT2 - mx * mx;
    float w = dsew[2 * i + g];
    double inv4 = 1.0 / sqrt((double)w * w * vx + (double)EPS_BN);
    cS4[tid] = (float)(w * inv4) * bng[tid];
    cO4[tid] = bnb[tid] - (float)(w * mx * inv4) * bng[tid];
  }
  __syncthreads();
  const int sub = tid >> 6, lane = tid & 63;
  const int n = blockIdx.x * 4 + sub;
  const int px = lane & 7, py = lane >> 3;
#pragma unroll
  for (int i = 0; i < 16; ++i) {
    const size_t base = ((size_t)n * 16 + i) * 256;
    f16x2 v01 = *(const f16x2*)&y2[base + (2 * py) * 16 + 2 * px];
    f16x2 v23 = *(const f16x2*)&y2[base + (2 * py + 1) * 16 + 2 * px];
    float a3 = cS3[i], c3 = cO3[i];
    float xr0 = fmaxf((float)v01[0] * a3 + c3, 0.f);
    float xr1 = fmaxf((float)v01[1] * a3 + c3, 0.f);
    float xr2 = fmaxf((float)v23[0] * a3 + c3, 0.f);
    float xr3 = fmaxf((float)v23[1] * a3 + c3, 0.f);
#pragma unroll
    for (int g = 0; g < 2; ++g) {
      const int c = 2 * i + g;
      float sc = cS4[c], of = cO4[c];
      float r0 = fmaxf(xr0 * sc + of, 0.f);
      float r1 = fmaxf(xr1 * sc + of, 0.f);
      float r2 = fmaxf(xr2 * sc + of, 0.f);
      float r3 = fmaxf(xr3 * sc + of, 0.f);
      h2[(size_t)n * 2048 + c * 64 + py * 8 + px] =
          f2bf(fmaxf(fmaxf(r0, r1), fmaxf(r2, r3)));
    }
  }
}

// cast fc1_w/fc2_w to bf16 (vectorized) + zero stat slots + conv1 wT table
__global__ __launch_bounds__(256) void k_cast_w(const float* __restrict__ w1,
                                                const float* __restrict__ w2,
                                                const float* __restrict__ dfe1,
                                                short* __restrict__ o1,
                                                short* __restrict__ o2,
                                                double* __restrict__ st,
                                                float* __restrict__ wt) {
  const int i4 = blockIdx.x * 256 + threadIdx.x;
  if (blockIdx.x == 0) {
    for (int k = threadIdx.x; k < 1664; k += 256) st[k] = 0.0;
    if (threadIdx.x < 216)
      wt[(threadIdx.x % 27) * 8 + threadIdx.x / 27] = dfe1[threadIdx.x];
  }
  if (i4 < 262144) {
    float4 v = ((const float4*)w1)[i4];
    short h[4] = {f2bf(v.x), f2bf(v.y), f2bf(v.z), f2bf(v.w)};
    ((uint2*)o1)[i4] = *(uint2*)h;
  } else if (i4 < 327680) {
    const int j = i4 - 262144;
    float4 v = ((const float4*)w2)[j];
    short h[4] = {f2bf(v.x), f2bf(v.y), f2bf(v.z), f2bf(v.w)};
    ((uint2*)o2)[j] = *(uint2*)h;
  }
}

// ------------- FC via LDS-staged MFMA GEMM ----------------------------------
// C[M,512] = act(A[M,K]bf16 @ W[512,K]bf16^T + b)
// block 64x64, BK=64, 4 waves (wave = 16 rows x 64 cols, 4 accs),
// double-buffered LDS staged via global_load_lds(16B).
// Swizzle (G21 both-sides): LDS linear dest; SOURCE col-seg XOR row&7;
// ds_read applies same XOR -> conflict-free 8-lane groups.
// XCD swizzle: 8 col-blocks of one row-strip -> same XCD (A-strip+W = 4MB=L2).
template <int K, int RELU, int OUT_BF16>
__global__ __launch_bounds__(256) void k_fc_lds(
    const short* __restrict__ A, const short* __restrict__ W,
    const float* __restrict__ bias, void* __restrict__ Cv) {
  // [buf][0:A|1:B][64 rows][64 shorts] = 32 KiB
  __shared__ __align__(16) short lds[2][2][64 * 64];
  const int tid = threadIdx.x, w = tid >> 6, lane = tid & 63;
  // grid (8,64); remap so xcd (= linear id % 8) == row-strip & 7
  const int id = blockIdx.y * 8 + blockIdx.x;
  const int bx = (id >> 3) & 7;
  const int by = ((id >> 6) << 3) | (id & 7);
  const int bm = by * 64, bn = bx * 64;
  const int cl = lane & 15, quad = lane >> 4;
  const int srow = lane >> 3, sseg = lane & 7;  // staging: 8 rows x 8 segs
  // wave w stages A rows / B cols [w*16 + j*8 .. +8), j=0,1.
  // source seg = sseg ^ (row&7) = sseg ^ srow (row strips are 8-aligned).
  const size_t soff = (size_t)srow * K + ((size_t)(sseg ^ srow) << 3);
  const short* aS0 = A + (size_t)(bm + w * 16) * K + soff;
  const short* aS1 = A + (size_t)(bm + w * 16 + 8) * K + soff;
  const short* bS0 = W + (size_t)(bn + w * 16) * K + soff;
  const short* bS1 = W + (size_t)(bn + w * 16 + 8) * K + soff;

#define GLD16(src, dst)                                                    \
  __builtin_amdgcn_global_load_lds(                                        \
      (const __attribute__((address_space(1))) void*)(const void*)(src),   \
      (__attribute__((address_space(3))) void*)(void*)(dst), 16, 0, 0)
#define STAGE(buf, k0)                                               \
  do {                                                               \
    GLD16(aS0 + (k0), &lds[buf][0][(w * 16) * 64]);                  \
    GLD16(aS1 + (k0), &lds[buf][0][(w * 16 + 8) * 64]);              \
    GLD16(bS0 + (k0), &lds[buf][1][(w * 16) * 64]);                  \
    GLD16(bS1 + (k0), &lds[buf][1][(w * 16 + 8) * 64]);              \
  } while (0)

  f32x4 acc[4];
#pragma unroll
  for (int ct = 0; ct < 4; ++ct) acc[ct] = (f32x4){0.f, 0.f, 0.f, 0.f};
  // frag read offsets (shorts), within A/B section
  int aOff[2], bOff0[2];
#pragma unroll
  for (int kk = 0; kk < 2; ++kk) {
    const int sw = ((kk * 4 + quad) ^ (cl & 7)) << 3;
    aOff[kk] = (w * 16 + cl) * 64 + sw;
    bOff0[kk] = cl * 64 + sw;  // + ct*16*64 per col-tile
  }
  constexpr int NT = K / 64;
  STAGE(0, 0);
#pragma unroll 2
  for (int t = 0; t < NT; ++t) {
    asm volatile("s_waitcnt vmcnt(0)" ::: "memory");
    __syncthreads();
    if (t + 1 < NT) STAGE((t + 1) & 1, (t + 1) * 64);
    const short* As = &lds[t & 1][0][0];
    const short* Bs = &lds[t & 1][1][0];
#pragma unroll
    for (int kk = 0; kk < 2; ++kk) {
      bf16x8 a = *(const bf16x8*)&As[aOff[kk]];
#pragma unroll
      for (int ct = 0; ct < 4; ++ct) {
        bf16x8 b = *(const bf16x8*)&Bs[bOff0[kk] + ct * 1024];
        acc[ct] = __builtin_amdgcn_mfma_f32_16x16x32_bf16(a, b, acc[ct], 0, 0, 0);
      }
    }
  }
#undef STAGE
#undef GLD16
#pragma unroll
  for (int ct = 0; ct < 4; ++ct) {
    const int col = bn + ct * 16 + cl;
    const float bia = bias[col];
#pragma unroll
    for (int r = 0; r < 4; ++r) {
      const int row = bm + w * 16 + quad * 4 + r;
      float v = acc[ct][r] + bia;
      if (RELU) v = fmaxf(v, 0.f);
      if (OUT_BF16)
        ((short*)Cv)[(size_t)row * 512 + col] = f2bf(v);
      else
        ((float*)Cv)[(size_t)row * 512 + col] = v;
    }
  }
}

// fc3: one wave per row, N=10, K=512, fp32
__global__ __launch_bounds__(256) void k_fc3(const float* __restrict__ A,
                                             const float* __restrict__ W,
                                             const float* __restrict__ b,
                                             float* __restrict__ out) {
  const int wid = threadIdx.x >> 6, lane = threadIdx.x & 63;
  const int row = blockIdx.x * 4 + wid;
  float p[10];
#pragma unroll
  for (int o = 0; o < 10; ++o) p[o] = 0.f;
  const float* a = A + (size_t)row * 512;
#pragma unroll
  for (int jj = 0; jj < 8; ++jj) {
    const int j = lane + jj * 64;
    float av = a[j];
#pragma unroll
    for (int o = 0; o < 10; ++o) p[o] += av * W[o * 512 + j];
  }
#pragma unroll
  for (int o = 0; o < 10; ++o) p[o] = wave_sum(p[o]);
  if (lane == 0) {
#pragma unroll
    for (int o = 0; o < 10; ++o) out[(size_t)row * 10 + o] = p[o] + b[o];
  }
}

}  // namespace

extern "C" void kernel_launch(void* const* d_in, const int* in_sizes, int n_in,
                              void* d_out, int out_size, void* d_ws,
                              size_t ws_size, hipStream_t stream) {
  const float* x      = (const float*)d_in[0];
  const float* dfe1_w = (const float*)d_in[1];
  const float* dse1_g = (const float*)d_in[2];
  const float* dse1_b = (const float*)d_in[3];
  const float* dse1_w = (const float*)d_in[4];
  const float* bn1_g  = (const float*)d_in[5];
  const float* bn1_b  = (const float*)d_in[6];
  const float* dfe2_w = (const float*)d_in[7];
  const float* dse2_g = (const float*)d_in[8];
  const float* dse2_b = (const float*)d_in[9];
  const float* dse2_w = (const float*)d_in[10];
  const float* bn2_g  = (const float*)d_in[11];
  const float* bn2_b  = (const float*)d_in[12];
  const float* fc1_w  = (const float*)d_in[13];
  const float* fc1_b  = (const float*)d_in[14];
  const float* fc2_w  = (const float*)d_in[15];
  const float* fc2_b  = (const float*)d_in[16];
  const float* fc3_w  = (const float*)d_in[17];
  const float* fc3_b  = (const float*)d_in[18];
  float* out = (float*)d_out;
  char* ws = (char*)d_ws;
  f16* y1 = (f16*)(ws + OFF_Y1);
  f16* y2 = (f16*)(ws + OFF_Y2);
  short* h2 = (short*)(ws + OFF_H2);
  short* a1 = (short*)(ws + OFF_A1);
  float* a2 = (float*)(ws + OFF_A2);
  short* wb1 = (short*)(ws + OFF_WB1);
  short* wb2 = (short*)(ws + OFF_WB2);
  float* wt1 = (float*)(ws + OFF_WT);
  double* st = (double*)(ws + OFF_ST);
  double* ST1 = st;                       // 128 slots: 8 banks x 16
  double* ST2 = st + (size_t)128 * 8;     // 16 slots
  double* ST3 = st + (size_t)144 * 8;     // 32 slots
  double* ST4 = st + (size_t)176 * 8;     // 32 slots

  k_cast_w<<<1280, 256, 0, stream>>>(fc1_w, fc2_w, dfe1_w, wb1, wb2, st, wt1);
  k_conv1_y1<<<2048, 256, 0, stream>>>(x, wt1, y1, ST1);
  k_xr1_stats<<<1024, 256, 0, stream>>>(y1, dse1_g, dse1_b, ST1, ST2);
  k_conv2_fused<<<1024, 512, 0, stream>>>(y1, dse1_g, dse1_b, dse1_w, bn1_g,
                                          bn1_b, dfe2_w, ST1, ST2, y2, ST3);
  k_xr2_stats<<<512, 256, 0, stream>>>(y2, dse2_g, dse2_b, ST3, ST4);
  k_l2_out<<<1024, 256, 0, stream>>>(y2, dse2_g, dse2_b, dse2_w, bn2_g, bn2_b,
                                     ST3, ST4, h2);
  k_fc_lds<2048, 1, 1><<<dim3(8, 64), 256, 0, stream>>>(h2, wb1, fc1_b, a1);
  k_fc_lds<512, 1, 0><<<dim3(8, 64), 256, 0, stream>>>(a1, wb2, fc2_b, a2);
  k_fc3<<<1024, 256, 0, stream>>>(a2, fc3_w, fc3_b, out);
}